// Round 12
// baseline (331.106 us; speedup 1.0000x reference)
//
#include <hip/hip_runtime.h>
#include <hip/hip_fp16.h>
#include <cstdint>
#include <cstddef>
#include <type_traits>

// ---------------- problem constants ----------------
constexpr int kN   = 50000;            // nodes
constexpr int kE   = 1600000;          // edges (before self loops)
constexpr int kET  = kE + kN;          // total edges incl self loops
constexpr float kNEG = 0.2f;
constexpr int NBUCK = (kN + 127) / 128;        // 391 buckets of 128 dst nodes
constexpr int CAPB  = 5120;                    // bucket capacity (mean 4220, +13 sigma)
constexpr int PCHUNK = 2048;                   // edges per partition block
constexpr int PGRID = (kET + PCHUNK - 1) / PCHUNK;
constexpr int QSTRIDE = kN * 32;               // halves per H2 quarter-shard (3.2 MB)

typedef _Float16 f16x8 __attribute__((ext_vector_type(8)));
typedef float    f32x4 __attribute__((ext_vector_type(4)));

// ---------------- CSR build: single-pass bucketed partition ----------------
__global__ __launch_bounds__(256) void partition_kernel(const int* __restrict__ ei,
                                                        int* __restrict__ bcnt,
                                                        unsigned* __restrict__ part) {
  __shared__ int hist[NBUCK];
  __shared__ int resv[NBUCK];
  __shared__ int lcnt[NBUCK];
  const int t = threadIdx.x;
  for (int i = t; i < NBUCK; i += 256) hist[i] = 0;
  __syncthreads();
  const int c0 = blockIdx.x * PCHUNK;
  const int cend = (c0 + PCHUNK < kET) ? c0 + PCHUNK : kET;
  for (int i = c0 + t; i < cend; i += 256) {
    const int dst = (i < kE) ? ei[kE + i] : (i - kE);
    atomicAdd(&hist[dst >> 7], 1);
  }
  __syncthreads();
  for (int i = t; i < NBUCK; i += 256) {
    lcnt[i] = 0;
    if (hist[i]) resv[i] = i * CAPB + atomicAdd(&bcnt[i], hist[i]);
  }
  __syncthreads();
  for (int i = c0 + t; i < cend; i += 256) {
    int src, dst;
    if (i < kE) { src = ei[i]; dst = ei[kE + i]; }
    else        { src = i - kE; dst = src; }
    const int b = dst >> 7;
    const int off = atomicAdd(&lcnt[b], 1);
    part[resv[b] + off] = ((unsigned)(dst & 127) << 16) | (unsigned)src;
  }
}

__global__ __launch_bounds__(512) void finalize_kernel(const unsigned* __restrict__ part,
                                                       const int* __restrict__ bcnt,
                                                       int* __restrict__ row_beg,
                                                       int* __restrict__ row_cnt,
                                                       int* __restrict__ col_src) {
  __shared__ int cnt[128];
  __shared__ int sc[128];
  __shared__ int nbase[128];
  const int b = blockIdx.x, t = threadIdx.x;
  const int lo = b * CAPB;
  const int hi = lo + bcnt[b];
  if (t < 128) cnt[t] = 0;
  __syncthreads();
  for (int j = lo + t; j < hi; j += 512) atomicAdd(&cnt[part[j] >> 16], 1);
  __syncthreads();
  if (t < 128) sc[t] = cnt[t];
  __syncthreads();
  for (int off = 1; off < 128; off <<= 1) {
    int v = 0;
    if (t < 128 && t >= off) v = sc[t - off];
    __syncthreads();
    if (t < 128) sc[t] += v;
    __syncthreads();
  }
  if (t < 128) {
    const int c = cnt[t];
    nbase[t] = lo + sc[t] - c;
    const int node = b * 128 + t;
    if (node < kN) { row_beg[node] = nbase[t]; row_cnt[node] = c; }
    cnt[t] = 0;
  }
  __syncthreads();
  for (int j = lo + t; j < hi; j += 512) {
    const unsigned v = part[j];
    const int nl = v >> 16;
    const int pos = nbase[nl] + atomicAdd(&cnt[nl], 1);
    col_src[pos] = (int)(v & 0xffffu);
  }
}

// ---------------- W prep: transpose + fp16 (Wt[c][k], k contiguous) ----------------
__global__ __launch_bounds__(256) void prep_w_kernel(
    const float* __restrict__ W0, const float* __restrict__ W1,
    const float* __restrict__ W2, __half* __restrict__ Wt0,
    __half* __restrict__ Wt1, __half* __restrict__ Wt2) {
  int i = blockIdx.x * 256 + threadIdx.x;
  const int stride = gridDim.x * 256;
  for (; i < 16384 * 2 + 4096; i += stride) {
    if (i < 16384) {
      const int k = i >> 7, c = i & 127;
      Wt0[c * 128 + k] = __float2half_rn(W0[i]);
    } else if (i < 32768) {
      const int j = i - 16384, k = j >> 7, c = j & 127;
      Wt1[c * 128 + k] = __float2half_rn(W1[j]);
    } else {
      const int j = i - 32768, k = j >> 5, c = j & 31;
      Wt2[c * 128 + k] = __float2half_rn(W2[j]);
    }
  }
}

// ---------------- MFMA transform + fused alpha ----------------
// MOUT=128: H2 QUARTER-MAJOR (shard q at q*QSTRIDE, rows of 32 halves).
// MOUT=32 : H2 flat [node][32].
template<int NCOL, typename TIN>
__global__ __launch_bounds__(256) void mfma_transform_kernel(
    const TIN* __restrict__ X, const __half* __restrict__ Wt,
    const float* __restrict__ asf, const float* __restrict__ adf,
    __half* __restrict__ H2, float2* __restrict__ AS, float2* __restrict__ AD, int n) {
  constexpr int NT = NCOL / 16;
  const int wid  = threadIdx.x >> 6;
  const int lane = threadIdx.x & 63;
  const int rbase = blockIdx.x * 64 + wid * 16;
  if (rbase >= n) return;
  const int r  = rbase + (lane & 15);
  const int kg = (lane >> 4) * 8;
  const _Float16* __restrict__ Wf = (const _Float16*)Wt;

  f32x4 acc[NT];
#pragma unroll
  for (int t = 0; t < NT; t++) acc[t] = (f32x4){0.f, 0.f, 0.f, 0.f};

#pragma unroll
  for (int kc = 0; kc < 4; kc++) {
    const int kh = kc * 32 + kg;
    f16x8 bfrag;
    if constexpr (std::is_same<TIN, float>::value) {
      const float4 v0 = *(const float4*)(X + (size_t)r * 128 + kh);
      const float4 v1 = *(const float4*)(X + (size_t)r * 128 + kh + 4);
      bfrag[0] = (_Float16)v0.x; bfrag[1] = (_Float16)v0.y;
      bfrag[2] = (_Float16)v0.z; bfrag[3] = (_Float16)v0.w;
      bfrag[4] = (_Float16)v1.x; bfrag[5] = (_Float16)v1.y;
      bfrag[6] = (_Float16)v1.z; bfrag[7] = (_Float16)v1.w;
    } else {
      bfrag = *(const f16x8*)((const _Float16*)X + (size_t)r * 128 + kh);
    }
#pragma unroll
    for (int t = 0; t < NT; t++) {
      const f16x8 afrag = *(const f16x8*)(Wf + (size_t)(t * 16 + (lane & 15)) * 128 + kh);
      acc[t] = __builtin_amdgcn_mfma_f32_16x16x32_f16(afrag, bfrag, acc[t], 0, 0, 0);
    }
  }

  const int c4 = (lane >> 4) * 4;
  float s0 = 0.f, s1 = 0.f, d0 = 0.f, d1 = 0.f;
#pragma unroll
  for (int t = 0; t < NT; t++) {
    const int c0 = t * 16 + c4;
    const float4 av = *(const float4*)(asf + c0);
    const float4 dv = *(const float4*)(adf + c0);
    const float ps = acc[t][0] * av.x + acc[t][1] * av.y + acc[t][2] * av.z + acc[t][3] * av.w;
    const float pd = acc[t][0] * dv.x + acc[t][1] * dv.y + acc[t][2] * dv.z + acc[t][3] * dv.w;
    if (t < NT / 2) { s0 += ps; d0 += pd; } else { s1 += ps; d1 += pd; }
    union { __half2 h[2]; uint2 u; } pk;
    pk.h[0] = __floats2half2_rn(acc[t][0], acc[t][1]);
    pk.h[1] = __floats2half2_rn(acc[t][2], acc[t][3]);
    if constexpr (NCOL == 128) {
      const int qq = c0 >> 5;              // quarter 0..3
      const int co = c0 & 31;              // halves offset within shard row
      *(uint2*)(H2 + (size_t)qq * QSTRIDE + (size_t)r * 32 + co) = pk.u;
    } else {
      *(uint2*)(H2 + (size_t)r * NCOL + c0) = pk.u;
    }
  }
#pragma unroll
  for (int off = 16; off <= 32; off <<= 1) {
    s0 += __shfl_xor(s0, off); s1 += __shfl_xor(s1, off);
    d0 += __shfl_xor(d0, off); d1 += __shfl_xor(d1, off);
  }
  if (lane < 16) {
    AS[rbase + lane] = make_float2(s0, s1);
    AD[rbase + lane] = make_float2(d0, d1);
  }
}

// ---------------- per-edge normalized weights (one wave per node; layers 0,1) ----------------
// rec[h][e] = src | (fp16(alpha_h_normalized) << 16).
__global__ __launch_bounds__(256) void weight_kernel(
    const float2* __restrict__ AS, const float2* __restrict__ AD,
    const int* __restrict__ row_beg, const int* __restrict__ row_cnt,
    const int* __restrict__ col_src,
    unsigned* __restrict__ rec0, unsigned* __restrict__ rec1) {
  const int wid  = threadIdx.x >> 6;
  const int lane = threadIdx.x & 63;
  const int node = blockIdx.x * 4 + wid;
  const int begin = row_beg[node];
  const int d = row_cnt[node];
  const float2 adn = AD[node];

  int srcv = 0;
  float w0 = 0.f, w1 = 0.f;
  if (lane < d) {
    srcv = col_src[begin + lane];
    const float2 a = AS[srcv];
    float e0 = a.x + adn.x; e0 = (e0 > 0.f) ? e0 : kNEG * e0;
    float e1 = a.y + adn.y; e1 = (e1 > 0.f) ? e1 : kNEG * e1;
    w0 = __expf(e0); w1 = __expf(e1);
  }
  float sum0 = w0, sum1 = w1;
  for (int j = 64 + lane; j < d; j += 64) {    // ultra-rare d>64 tail
    const int s = col_src[begin + j];
    const float2 a = AS[s];
    float e0 = a.x + adn.x; e0 = (e0 > 0.f) ? e0 : kNEG * e0;
    float e1 = a.y + adn.y; e1 = (e1 > 0.f) ? e1 : kNEG * e1;
    sum0 += __expf(e0); sum1 += __expf(e1);
  }
#pragma unroll
  for (int off = 32; off >= 1; off >>= 1) {
    sum0 += __shfl_xor(sum0, off);
    sum1 += __shfl_xor(sum1, off);
  }
  const float inv0 = 1.0f / (sum0 + 1e-16f);
  const float inv1 = 1.0f / (sum1 + 1e-16f);
  if (lane < d) {
    const unsigned h0 = (unsigned)__half_as_ushort(__float2half_rn(w0 * inv0));
    const unsigned h1 = (unsigned)__half_as_ushort(__float2half_rn(w1 * inv1));
    rec0[begin + lane] = (unsigned)srcv | (h0 << 16);
    rec1[begin + lane] = (unsigned)srcv | (h1 << 16);
  }
  for (int j = 64 + lane; j < d; j += 64) {    // ultra-rare tail writes
    const int s = col_src[begin + j];
    const float2 a = AS[s];
    float e0 = a.x + adn.x; e0 = (e0 > 0.f) ? e0 : kNEG * e0;
    float e1 = a.y + adn.y; e1 = (e1 > 0.f) ? e1 : kNEG * e1;
    const unsigned h0 = (unsigned)__half_as_ushort(__float2half_rn(__expf(e0) * inv0));
    const unsigned h1 = (unsigned)__half_as_ushort(__float2half_rn(__expf(e1) * inv1));
    rec0[begin + j] = (unsigned)s | (h0 << 16);
    rec1[begin + j] = (unsigned)s | (h1 << 16);
  }
}

// ---------------- aggregate, quarter-sharded (C=64 layers) ----------------
// Wave per (node, quarter); shard 3.2 MB L2-resident per XCD-pair.
// Weights PRE-NORMALIZED in rec (no softmax here). rec loaded once coalesced;
// d<=64 path is loop-free: 4-deep unrolled (4 shfl + 4 perm + 4 uint4 loads +
// 16 hfma2), fp16 packed stream-reduce (softmax-normalized partials ~0.1 ->
// fp16 tree error well below bf16 output quantization).
__global__ __launch_bounds__(256) void agg64q_kernel(
    const __half* __restrict__ H2q, const unsigned* __restrict__ rec0,
    const unsigned* __restrict__ rec1, const int* __restrict__ row_beg,
    const int* __restrict__ row_cnt, const float* __restrict__ bias,
    __half* __restrict__ OUT) {
  const int bid = blockIdx.x;
  const int qtr = (bid & 7) >> 1;                  // quarter 0..3 -> XCD pair
  const int ng  = ((bid >> 3) << 1) | (bid & 1);   // node group (bijective)
  const int wid  = threadIdx.x >> 6;
  const int lane = threadIdx.x & 63;
  const int node = ng * 4 + wid;
  const int begin = row_beg[node];
  const int d = row_cnt[node];
  const unsigned* __restrict__ rec = (qtr >= 2) ? rec1 : rec0;
  const __half* __restrict__ Hq = H2q + (size_t)qtr * QSTRIDE;
  const int strm = lane >> 2;        // edge-stream 0..15
  const int cq   = lane & 3;         // 16B slice of the 64B quarter row

  // one coalesced rec load; 0 for lanes >= d (w=0, src=0 -> contributes 0)
  const unsigned recreg = (lane < d) ? rec[begin + lane] : 0u;

  __half2 hz; *(unsigned*)&hz = 0u;
  __half2 hc0 = hz, hc1 = hz, hc2 = hz, hc3 = hz;
  {
    // 4-deep, loop-free for d<=64: edges strm, 16+strm, 32+strm, 48+strm
    const unsigned r0 = (unsigned)__shfl((int)recreg, strm);
    const unsigned r1 = (unsigned)__shfl((int)recreg, 16 + strm);
    const unsigned r2 = (unsigned)__shfl((int)recreg, 32 + strm);
    const unsigned r3 = (unsigned)__shfl((int)recreg, 48 + strm);
    union { uint4 u; __half2 h[4]; } v0, v1, v2, v3;
    v0.u = *(const uint4*)(Hq + (size_t)(r0 & 0xffffu) * 32 + (cq << 3));
    v1.u = *(const uint4*)(Hq + (size_t)(r1 & 0xffffu) * 32 + (cq << 3));
    v2.u = *(const uint4*)(Hq + (size_t)(r2 & 0xffffu) * 32 + (cq << 3));
    v3.u = *(const uint4*)(Hq + (size_t)(r3 & 0xffffu) * 32 + (cq << 3));
    union { unsigned u; __half2 h; } w0, w1, w2, w3;
    w0.u = __builtin_amdgcn_perm(r0, r0, 0x03020302u);
    w1.u = __builtin_amdgcn_perm(r1, r1, 0x03020302u);
    w2.u = __builtin_amdgcn_perm(r2, r2, 0x03020302u);
    w3.u = __builtin_amdgcn_perm(r3, r3, 0x03020302u);
    hc0 = __hfma2(w0.h, v0.h[0], hc0); hc1 = __hfma2(w0.h, v0.h[1], hc1);
    hc2 = __hfma2(w0.h, v0.h[2], hc2); hc3 = __hfma2(w0.h, v0.h[3], hc3);
    hc0 = __hfma2(w1.h, v1.h[0], hc0); hc1 = __hfma2(w1.h, v1.h[1], hc1);
    hc2 = __hfma2(w1.h, v1.h[2], hc2); hc3 = __hfma2(w1.h, v1.h[3], hc3);
    hc0 = __hfma2(w2.h, v2.h[0], hc0); hc1 = __hfma2(w2.h, v2.h[1], hc1);
    hc2 = __hfma2(w2.h, v2.h[2], hc2); hc3 = __hfma2(w2.h, v2.h[3], hc3);
    hc0 = __hfma2(w3.h, v3.h[0], hc0); hc1 = __hfma2(w3.h, v3.h[1], hc1);
    hc2 = __hfma2(w3.h, v3.h[2], hc2); hc3 = __hfma2(w3.h, v3.h[3], hc3);
  }
  for (int jt = 64 + strm; jt < d; jt += 16) {     // ultra-rare d>64 fallback
    const unsigned r = rec[begin + jt];
    union { unsigned u; __half2 h; } wv;
    wv.u = __builtin_amdgcn_perm(r, r, 0x03020302u);
    union { uint4 u; __half2 h[4]; } raw;
    raw.u = *(const uint4*)(Hq + (size_t)(r & 0xffffu) * 32 + (cq << 3));
    hc0 = __hfma2(wv.h, raw.h[0], hc0);
    hc1 = __hfma2(wv.h, raw.h[1], hc1);
    hc2 = __hfma2(wv.h, raw.h[2], hc2);
    hc3 = __hfma2(wv.h, raw.h[3], hc3);
  }
  // fp16 packed reduce over 16 streams (lanes differing in bits 2..5)
#pragma unroll
  for (int off = 4; off <= 32; off <<= 1) {
    union { __half2 h; int i; } a0, a1, a2, a3;
    a0.h = hc0; a1.h = hc1; a2.h = hc2; a3.h = hc3;
    a0.i = __shfl_xor(a0.i, off); a1.i = __shfl_xor(a1.i, off);
    a2.i = __shfl_xor(a2.i, off); a3.i = __shfl_xor(a3.i, off);
    hc0 = __hadd2(hc0, a0.h); hc1 = __hadd2(hc1, a1.h);
    hc2 = __hadd2(hc2, a2.h); hc3 = __hadd2(hc3, a3.h);
  }
  if (lane < 4) {
    const int ch = qtr * 32 + lane * 8;
    const float4 b0v = *(const float4*)(bias + ch);
    const float4 b1v = *(const float4*)(bias + ch + 4);
    const float2 f0 = __half22float2(hc0);
    const float2 f1 = __half22float2(hc1);
    const float2 f2 = __half22float2(hc2);
    const float2 f3 = __half22float2(hc3);
    float4 o0, o1;
    o0.x = f0.x + b0v.x; o0.y = f0.y + b0v.y; o0.z = f1.x + b0v.z; o0.w = f1.y + b0v.w;
    o1.x = f2.x + b1v.x; o1.y = f2.y + b1v.y; o1.z = f3.x + b1v.z; o1.w = f3.y + b1v.w;
    o0.x = (o0.x > 0.f) ? o0.x : expm1f(o0.x);
    o0.y = (o0.y > 0.f) ? o0.y : expm1f(o0.y);
    o0.z = (o0.z > 0.f) ? o0.z : expm1f(o0.z);
    o0.w = (o0.w > 0.f) ? o0.w : expm1f(o0.w);
    o1.x = (o1.x > 0.f) ? o1.x : expm1f(o1.x);
    o1.y = (o1.y > 0.f) ? o1.y : expm1f(o1.y);
    o1.z = (o1.z > 0.f) ? o1.z : expm1f(o1.z);
    o1.w = (o1.w > 0.f) ? o1.w : expm1f(o1.w);
    union { __half2 h[4]; uint4 u; } pk;
    pk.h[0] = __floats2half2_rn(o0.x, o0.y);
    pk.h[1] = __floats2half2_rn(o0.z, o0.w);
    pk.h[2] = __floats2half2_rn(o1.x, o1.y);
    pk.h[3] = __floats2half2_rn(o1.z, o1.w);
    *(uint4*)(OUT + (size_t)node * 128 + ch) = pk.u;
  }
}

// ---------------- aggregate, final layer (C=16; fused softmax, flat 3.2MB table) ----------------
__global__ __launch_bounds__(256) void agg16_kernel(
    const __half* __restrict__ H2, const float2* __restrict__ AS,
    const float2* __restrict__ AD, const int* __restrict__ row_beg,
    const int* __restrict__ row_cnt, const int* __restrict__ col_src,
    const float* __restrict__ bias, float* __restrict__ OUT) {
  const int wid  = threadIdx.x >> 6;
  const int lane = threadIdx.x & 63;
  const int node = blockIdx.x * 4 + wid;
  const int begin = row_beg[node];
  const int d = row_cnt[node];
  const float2 adn = AD[node];

  int srcv = 0;
  unsigned pkw = 0;
  float sum0 = 0.f, sum1 = 0.f;
  if (lane < d) {
    srcv = col_src[begin + lane];
    const float2 a = AS[srcv];
    float e0 = a.x + adn.x; e0 = (e0 > 0.f) ? e0 : kNEG * e0;
    float e1 = a.y + adn.y; e1 = (e1 > 0.f) ? e1 : kNEG * e1;
    sum0 = __expf(e0); sum1 = __expf(e1);
    const __half2 ph = __floats2half2_rn(sum0, sum1);
    pkw = *(const unsigned*)&ph;
  }
  for (int j = 64 + lane; j < d; j += 64) {
    const int s = col_src[begin + j];
    const float2 a = AS[s];
    float e0 = a.x + adn.x; e0 = (e0 > 0.f) ? e0 : kNEG * e0;
    float e1 = a.y + adn.y; e1 = (e1 > 0.f) ? e1 : kNEG * e1;
    sum0 += __expf(e0); sum1 += __expf(e1);
  }
#pragma unroll
  for (int off = 32; off >= 1; off >>= 1) {
    sum0 += __shfl_xor(sum0, off);
    sum1 += __shfl_xor(sum1, off);
  }
  const float inv0 = 1.0f / (sum0 + 1e-16f);
  const float inv1 = 1.0f / (sum1 + 1e-16f);

  const int dr = (d < 64) ? d : 64;
  const int e = lane >> 3;        // edge-stream 0..7
  const int q = lane & 7;         // channels 4q..4q+3
  const int hsel = (q >= 4);
  const unsigned sel = hsel ? 0x03020302u : 0x01000100u;
  const float inv = hsel ? inv1 : inv0;
  __half2 hz; *(unsigned*)&hz = 0u;
  __half2 hc0 = hz, hc1 = hz;
  for (int j = 0; j < dr; j += 16) {
    const int j0 = j + e, j1 = j + 8 + e;              // <= 63 always
    const int s0 = __shfl(srcv, j0), s1 = __shfl(srcv, j1);
    const unsigned p0 = __shfl((int)pkw, j0), p1 = __shfl((int)pkw, j1);
    union { unsigned u; __half2 h; } w0, w1;
    w0.u = __builtin_amdgcn_perm(p0, p0, sel);
    w1.u = __builtin_amdgcn_perm(p1, p1, sel);
    union { uint2 u; __half2 h[2]; } r0, r1;
    r0.u = *(const uint2*)(H2 + (size_t)s0 * 32 + 4 * q);
    r1.u = *(const uint2*)(H2 + (size_t)s1 * 32 + 4 * q);
    hc0 = __hfma2(w0.h, r0.h[0], hc0); hc1 = __hfma2(w0.h, r0.h[1], hc1);
    hc0 = __hfma2(w1.h, r1.h[0], hc0); hc1 = __hfma2(w1.h, r1.h[1], hc1);
  }
  float4 acc;
  float2 f;
  f = __half22float2(hc0); acc.x = f.x; acc.y = f.y;
  f = __half22float2(hc1); acc.z = f.x; acc.w = f.y;
  for (int jt = 64 + e; jt < d; jt += 8) {   // ultra-rare fallback
    const int s = col_src[begin + jt];
    const float2 a = AS[s];
    float e0 = a.x + adn.x; e0 = (e0 > 0.f) ? e0 : kNEG * e0;
    float e1 = a.y + adn.y; e1 = (e1 > 0.f) ? e1 : kNEG * e1;
    const float w = hsel ? __expf(e1) : __expf(e0);
    union { uint2 u; __half2 h[2]; } raw;
    raw.u = *(const uint2*)(H2 + (size_t)s * 32 + 4 * q);
    const float2 f0 = __half22float2(raw.h[0]);
    const float2 f1 = __half22float2(raw.h[1]);
    acc.x = fmaf(w, f0.x, acc.x); acc.y = fmaf(w, f0.y, acc.y);
    acc.z = fmaf(w, f1.x, acc.z); acc.w = fmaf(w, f1.y, acc.w);
  }
#pragma unroll
  for (int off = 32; off >= 8; off >>= 1) {
    acc.x += __shfl_xor(acc.x, off); acc.y += __shfl_xor(acc.y, off);
    acc.z += __shfl_xor(acc.z, off); acc.w += __shfl_xor(acc.w, off);
  }
  acc.x *= inv; acc.y *= inv; acc.z *= inv; acc.w *= inv;
  const float px = __shfl_xor(acc.x, 4);
  const float py = __shfl_xor(acc.y, 4);
  const float pz = __shfl_xor(acc.z, 4);
  const float pw2 = __shfl_xor(acc.w, 4);
  if (lane < 4) {
    const int ch = 4 * q;
    const float4 bv = *(const float4*)(bias + ch);
    float4 o;
    o.x = 0.5f * (acc.x + px) + bv.x;
    o.y = 0.5f * (acc.y + py) + bv.y;
    o.z = 0.5f * (acc.z + pz) + bv.z;
    o.w = 0.5f * (acc.w + pw2) + bv.w;
    *(float4*)(OUT + (size_t)node * 16 + ch) = o;
  }
}

// ---------------- host launcher ----------------
extern "C" void kernel_launch(void* const* d_in, const int* in_sizes, int n_in,
                              void* d_out, int out_size, void* d_ws, size_t ws_size,
                              hipStream_t stream) {
  const float* x   = (const float*)d_in[0];
  const int*   ei  = (const int*)d_in[1];
  const float* W0  = (const float*)d_in[2];
  const float* as0 = (const float*)d_in[3];
  const float* ad0 = (const float*)d_in[4];
  const float* b0  = (const float*)d_in[5];
  const float* W1  = (const float*)d_in[6];
  const float* as1 = (const float*)d_in[7];
  const float* ad1 = (const float*)d_in[8];
  const float* b1  = (const float*)d_in[9];
  const float* W2  = (const float*)d_in[10];
  const float* as2 = (const float*)d_in[11];
  const float* ad2 = (const float*)d_in[12];
  const float* b2  = (const float*)d_in[13];
  float* out = (float*)d_out;

  size_t off = 0;
  auto alloc = [&](size_t bytes) -> void* {
    void* p = (char*)d_ws + off;
    off += (bytes + 255) & ~(size_t)255;
    return p;
  };
  int*      row_beg = (int*)alloc(sizeof(int) * kN);
  int*      row_cnt = (int*)alloc(sizeof(int) * kN);
  int*      bcnt    = (int*)alloc(sizeof(int) * NBUCK);
  int*      col_src = (int*)alloc(sizeof(int) * (size_t)NBUCK * CAPB);
  unsigned* rec0    = (unsigned*)alloc(sizeof(unsigned) * (size_t)NBUCK * CAPB);
  unsigned* rec1    = (unsigned*)alloc(sizeof(unsigned) * (size_t)NBUCK * CAPB);
  float2*   AS      = (float2*)alloc(sizeof(float2) * kN);
  float2*   AD      = (float2*)alloc(sizeof(float2) * kN);
  __half*   H2      = (__half*)alloc(sizeof(__half) * (size_t)kN * 128);
  __half*   actA    = (__half*)alloc(sizeof(__half) * (size_t)kN * 128);
  __half*   actB    = (__half*)alloc(sizeof(__half) * (size_t)kN * 128);
  __half*   Wt0     = (__half*)alloc(sizeof(__half) * 128 * 128);
  __half*   Wt1     = (__half*)alloc(sizeof(__half) * 128 * 128);
  __half*   Wt2     = (__half*)alloc(sizeof(__half) * 32 * 128);
  unsigned* part    = (unsigned*)actA;   // 8MB <= 12.8MB; dead before layer-0 agg writes actA
  (void)ws_size; (void)in_sizes; (void)n_in; (void)out_size;

  // ---- CSR build + W prep (edge list identical for all layers) ----
  hipMemsetAsync(bcnt, 0, sizeof(int) * NBUCK, stream);
  prep_w_kernel<<<144, 256, 0, stream>>>(W0, W1, W2, Wt0, Wt1, Wt2);
  partition_kernel<<<PGRID, 256, 0, stream>>>(ei, bcnt, part);
  finalize_kernel<<<NBUCK, 512, 0, stream>>>(part, bcnt, row_beg, row_cnt, col_src);

  const int tgrid = (kN + 63) / 64;   // 782
  const int ngrid = kN / 4;           // 12500

  // ---- layer 0 ----
  mfma_transform_kernel<128, float><<<tgrid, 256, 0, stream>>>(x, Wt0, as0, ad0, H2, AS, AD, kN);
  weight_kernel<<<ngrid, 256, 0, stream>>>(AS, AD, row_beg, row_cnt, col_src, rec0, rec1);
  agg64q_kernel<<<kN, 256, 0, stream>>>(H2, rec0, rec1, row_beg, row_cnt, b0, actA);

  // ---- layer 1 ----
  mfma_transform_kernel<128, __half><<<tgrid, 256, 0, stream>>>(actA, Wt1, as1, ad1, H2, AS, AD, kN);
  weight_kernel<<<ngrid, 256, 0, stream>>>(AS, AD, row_beg, row_cnt, col_src, rec0, rec1);
  agg64q_kernel<<<kN, 256, 0, stream>>>(H2, rec0, rec1, row_beg, row_cnt, b1, actB);

  // ---- layer 2 ----
  mfma_transform_kernel<32, __half><<<tgrid, 256, 0, stream>>>(actB, Wt2, as2, ad2, H2, AS, AD, kN);
  agg16_kernel<<<ngrid, 256, 0, stream>>>(H2, AS, AD, row_beg, row_cnt, col_src, b2, out);
}

// Round 13
// 257.373 us; speedup vs baseline: 1.2865x; 1.2865x over previous
//
#include <hip/hip_runtime.h>
#include <hip/hip_fp16.h>
#include <cstdint>
#include <cstddef>
#include <type_traits>

// ---------------- problem constants ----------------
constexpr int kN   = 50000;            // nodes
constexpr int kE   = 1600000;          // edges (before self loops)
constexpr int kET  = kE + kN;          // total edges incl self loops
constexpr float kNEG = 0.2f;
constexpr int NBUCK = (kN + 127) / 128;        // 391 buckets of 128 dst nodes
constexpr int CAPB  = 5120;                    // bucket capacity (mean 4220, +13 sigma)
constexpr int PCHUNK = 2048;                   // edges per partition block
constexpr int PGRID = (kET + PCHUNK - 1) / PCHUNK;

typedef _Float16 f16x8 __attribute__((ext_vector_type(8)));
typedef float    f32x4 __attribute__((ext_vector_type(4)));

// ---------------- CSR build: single-pass bucketed partition ----------------
__global__ __launch_bounds__(256) void partition_kernel(const int* __restrict__ ei,
                                                        int* __restrict__ bcnt,
                                                        unsigned* __restrict__ part) {
  __shared__ int hist[NBUCK];
  __shared__ int resv[NBUCK];
  __shared__ int lcnt[NBUCK];
  const int t = threadIdx.x;
  for (int i = t; i < NBUCK; i += 256) hist[i] = 0;
  __syncthreads();
  const int c0 = blockIdx.x * PCHUNK;
  const int cend = (c0 + PCHUNK < kET) ? c0 + PCHUNK : kET;
  for (int i = c0 + t; i < cend; i += 256) {
    const int dst = (i < kE) ? ei[kE + i] : (i - kE);
    atomicAdd(&hist[dst >> 7], 1);
  }
  __syncthreads();
  for (int i = t; i < NBUCK; i += 256) {
    lcnt[i] = 0;
    if (hist[i]) resv[i] = i * CAPB + atomicAdd(&bcnt[i], hist[i]);
  }
  __syncthreads();
  for (int i = c0 + t; i < cend; i += 256) {
    int src, dst;
    if (i < kE) { src = ei[i]; dst = ei[kE + i]; }
    else        { src = i - kE; dst = src; }
    const int b = dst >> 7;
    const int off = atomicAdd(&lcnt[b], 1);
    part[resv[b] + off] = ((unsigned)(dst & 127) << 16) | (unsigned)src;
  }
}

__global__ __launch_bounds__(512) void finalize_kernel(const unsigned* __restrict__ part,
                                                       const int* __restrict__ bcnt,
                                                       int* __restrict__ row_beg,
                                                       int* __restrict__ row_cnt,
                                                       int* __restrict__ col_src) {
  __shared__ int cnt[128];
  __shared__ int sc[128];
  __shared__ int nbase[128];
  const int b = blockIdx.x, t = threadIdx.x;
  const int lo = b * CAPB;
  const int hi = lo + bcnt[b];
  if (t < 128) cnt[t] = 0;
  __syncthreads();
  for (int j = lo + t; j < hi; j += 512) atomicAdd(&cnt[part[j] >> 16], 1);
  __syncthreads();
  if (t < 128) sc[t] = cnt[t];
  __syncthreads();
  for (int off = 1; off < 128; off <<= 1) {
    int v = 0;
    if (t < 128 && t >= off) v = sc[t - off];
    __syncthreads();
    if (t < 128) sc[t] += v;
    __syncthreads();
  }
  if (t < 128) {
    const int c = cnt[t];
    nbase[t] = lo + sc[t] - c;
    const int node = b * 128 + t;
    if (node < kN) { row_beg[node] = nbase[t]; row_cnt[node] = c; }
    cnt[t] = 0;
  }
  __syncthreads();
  for (int j = lo + t; j < hi; j += 512) {
    const unsigned v = part[j];
    const int nl = v >> 16;
    const int pos = nbase[nl] + atomicAdd(&cnt[nl], 1);
    col_src[pos] = (int)(v & 0xffffu);
  }
}

// ---------------- W prep: transpose + fp16 (Wt[c][k], k contiguous); zero bcnt ----------------
__global__ __launch_bounds__(256) void prep_w_kernel(
    const float* __restrict__ W0, const float* __restrict__ W1,
    const float* __restrict__ W2, __half* __restrict__ Wt0,
    __half* __restrict__ Wt1, __half* __restrict__ Wt2, int* __restrict__ bcnt) {
  int i = blockIdx.x * 256 + threadIdx.x;
  const int stride = gridDim.x * 256;
  if (i < NBUCK) bcnt[i] = 0;
  for (; i < 16384 * 2 + 4096; i += stride) {
    if (i < 16384) {
      const int k = i >> 7, c = i & 127;
      Wt0[c * 128 + k] = __float2half_rn(W0[i]);
    } else if (i < 32768) {
      const int j = i - 16384, k = j >> 7, c = j & 127;
      Wt1[c * 128 + k] = __float2half_rn(W1[j]);
    } else {
      const int j = i - 32768, k = j >> 5, c = j & 31;
      Wt2[c * 128 + k] = __float2half_rn(W2[j]);
    }
  }
}

// ---------------- MFMA transform + fused alpha ----------------
// H2[r][c] (fp16 flat) = X[r][:] @ W[:, c], via mfma_f32_16x16x32_f16 with
// A = Wt rows (c is the M-dim -> lane holds 4 consecutive c), B = X rows.
template<int NCOL, typename TIN>
__global__ __launch_bounds__(256) void mfma_transform_kernel(
    const TIN* __restrict__ X, const __half* __restrict__ Wt,
    const float* __restrict__ asf, const float* __restrict__ adf,
    __half* __restrict__ H2, float2* __restrict__ AS, float2* __restrict__ AD, int n) {
  constexpr int NT = NCOL / 16;
  const int wid  = threadIdx.x >> 6;
  const int lane = threadIdx.x & 63;
  const int rbase = blockIdx.x * 64 + wid * 16;
  if (rbase >= n) return;
  const int r  = rbase + (lane & 15);
  const int kg = (lane >> 4) * 8;
  const _Float16* __restrict__ Wf = (const _Float16*)Wt;

  f32x4 acc[NT];
#pragma unroll
  for (int t = 0; t < NT; t++) acc[t] = (f32x4){0.f, 0.f, 0.f, 0.f};

#pragma unroll
  for (int kc = 0; kc < 4; kc++) {
    const int kh = kc * 32 + kg;
    f16x8 bfrag;
    if constexpr (std::is_same<TIN, float>::value) {
      const float4 v0 = *(const float4*)(X + (size_t)r * 128 + kh);
      const float4 v1 = *(const float4*)(X + (size_t)r * 128 + kh + 4);
      bfrag[0] = (_Float16)v0.x; bfrag[1] = (_Float16)v0.y;
      bfrag[2] = (_Float16)v0.z; bfrag[3] = (_Float16)v0.w;
      bfrag[4] = (_Float16)v1.x; bfrag[5] = (_Float16)v1.y;
      bfrag[6] = (_Float16)v1.z; bfrag[7] = (_Float16)v1.w;
    } else {
      bfrag = *(const f16x8*)((const _Float16*)X + (size_t)r * 128 + kh);
    }
#pragma unroll
    for (int t = 0; t < NT; t++) {
      const f16x8 afrag = *(const f16x8*)(Wf + (size_t)(t * 16 + (lane & 15)) * 128 + kh);
      acc[t] = __builtin_amdgcn_mfma_f32_16x16x32_f16(afrag, bfrag, acc[t], 0, 0, 0);
    }
  }

  // epilogue: H2 store (4 consecutive channels / lane / tile) + alpha partials
  const int c4 = (lane >> 4) * 4;
  float s0 = 0.f, s1 = 0.f, d0 = 0.f, d1 = 0.f;
#pragma unroll
  for (int t = 0; t < NT; t++) {
    const int c0 = t * 16 + c4;
    const float4 av = *(const float4*)(asf + c0);
    const float4 dv = *(const float4*)(adf + c0);
    const float ps = acc[t][0] * av.x + acc[t][1] * av.y + acc[t][2] * av.z + acc[t][3] * av.w;
    const float pd = acc[t][0] * dv.x + acc[t][1] * dv.y + acc[t][2] * dv.z + acc[t][3] * dv.w;
    if (t < NT / 2) { s0 += ps; d0 += pd; } else { s1 += ps; d1 += pd; }
    union { __half2 h[2]; uint2 u; } pk;
    pk.h[0] = __floats2half2_rn(acc[t][0], acc[t][1]);
    pk.h[1] = __floats2half2_rn(acc[t][2], acc[t][3]);
    *(uint2*)(H2 + (size_t)r * NCOL + c0) = pk.u;
  }
#pragma unroll
  for (int off = 16; off <= 32; off <<= 1) {
    s0 += __shfl_xor(s0, off); s1 += __shfl_xor(s1, off);
    d0 += __shfl_xor(d0, off); d1 += __shfl_xor(d1, off);
  }
  if (lane < 16) {
    AS[rbase + lane] = make_float2(s0, s1);
    AD[rbase + lane] = make_float2(d0, d1);
  }
}

// ---------------- fused softmax + aggregate (barrier-free, wave-per-node) ----------------
// Weights in REGISTERS (one edge per lane, d<=64 fast path); gather is 2-stage
// software-pipelined: stage(j+16) loads are issued before compute(j) consumes —
// 8 uint4 loads in flight per wave.
// MODE 0 (C=64): OUT[n,128]=elu(agg+bias) fp16; 4 streams x 16 lanes x 16B.
// MODE 1 (C=16): OUT[n,16]=mean_heads(agg)+b fp32; 8 streams x 8 lanes x 8B.
template<int C, int MODE, typename TOUT>
__global__ __launch_bounds__(256) void agg_kernel(
    const __half* __restrict__ H2, const float2* __restrict__ AS,
    const float2* __restrict__ AD, const int* __restrict__ row_beg,
    const int* __restrict__ row_cnt, const int* __restrict__ col_src,
    const float* __restrict__ bias, TOUT* __restrict__ OUT) {
  const int wid  = threadIdx.x >> 6;
  const int lane = threadIdx.x & 63;
  const int node = blockIdx.x * 4 + wid;

  const int begin = row_beg[node];
  const int d = row_cnt[node];
  const float2 adn = AD[node];

  // ---- pass A: one edge per lane, weights in registers ----
  int srcv = 0;
  unsigned pkw = 0;                 // half2: low = w_head0, high = w_head1
  float sum0 = 0.f, sum1 = 0.f;
  if (lane < d) {
    srcv = col_src[begin + lane];
    const float2 a = AS[srcv];
    float e0 = a.x + adn.x; e0 = (e0 > 0.f) ? e0 : kNEG * e0;
    float e1 = a.y + adn.y; e1 = (e1 > 0.f) ? e1 : kNEG * e1;
    sum0 = __expf(e0); sum1 = __expf(e1);
    const __half2 ph = __floats2half2_rn(sum0, sum1);
    pkw = *(const unsigned*)&ph;
  }
  for (int j = 64 + lane; j < d; j += 64) {    // ultra-rare d>64 tail (sums only)
    const int s = col_src[begin + j];
    const float2 a = AS[s];
    float e0 = a.x + adn.x; e0 = (e0 > 0.f) ? e0 : kNEG * e0;
    float e1 = a.y + adn.y; e1 = (e1 > 0.f) ? e1 : kNEG * e1;
    sum0 += __expf(e0); sum1 += __expf(e1);
  }
#pragma unroll
  for (int off = 32; off >= 1; off >>= 1) {
    sum0 += __shfl_xor(sum0, off);
    sum1 += __shfl_xor(sum1, off);
  }
  const float inv0 = 1.0f / (sum0 + 1e-16f);
  const float inv1 = 1.0f / (sum1 + 1e-16f);

  const int dr = (d < 64) ? d : 64;            // register-held edges (>=1: self-loop)

  if constexpr (MODE == 0) {
    const int e = lane >> 4;        // edge-stream 0..3
    const int q = lane & 15;        // channels 8q..8q+7
    const int hsel = (q >= 8);
    const unsigned sel = hsel ? 0x03020302u : 0x01000100u;
    const float inv = hsel ? inv1 : inv0;
    float4 a0 = make_float4(0.f, 0.f, 0.f, 0.f);
    float4 a1 = make_float4(0.f, 0.f, 0.f, 0.f);

    uint4 va[4], vb[4];
    unsigned pa[4], pb[4];
    auto stage = [&](int j, uint4* v, unsigned* p) {
      const int j0 = j + e, j1 = j + 4 + e, j2 = j + 8 + e, j3 = j + 12 + e;
      const int s0 = __shfl(srcv, j0), s1 = __shfl(srcv, j1),
                s2 = __shfl(srcv, j2), s3 = __shfl(srcv, j3);
      p[0] = (unsigned)__shfl((int)pkw, j0); p[1] = (unsigned)__shfl((int)pkw, j1);
      p[2] = (unsigned)__shfl((int)pkw, j2); p[3] = (unsigned)__shfl((int)pkw, j3);
      v[0] = *(const uint4*)(H2 + (size_t)s0 * 128 + 8 * q);
      v[1] = *(const uint4*)(H2 + (size_t)s1 * 128 + 8 * q);
      v[2] = *(const uint4*)(H2 + (size_t)s2 * 128 + 8 * q);
      v[3] = *(const uint4*)(H2 + (size_t)s3 * 128 + 8 * q);
    };
    auto compute = [&](const uint4* v, const unsigned* p) {
      union { unsigned u; __half2 h; } w0, w1, w2, w3;
      w0.u = __builtin_amdgcn_perm(p[0], p[0], sel);
      w1.u = __builtin_amdgcn_perm(p[1], p[1], sel);
      w2.u = __builtin_amdgcn_perm(p[2], p[2], sel);
      w3.u = __builtin_amdgcn_perm(p[3], p[3], sel);
      const __half2* h0 = (const __half2*)&v[0];
      const __half2* h1 = (const __half2*)&v[1];
      const __half2* h2 = (const __half2*)&v[2];
      const __half2* h3 = (const __half2*)&v[3];
      __half2 hz; *(unsigned*)&hz = 0u;
      __half2 hc0 = hz, hc1 = hz, hc2 = hz, hc3 = hz;
      hc0 = __hfma2(w0.h, h0[0], hc0); hc1 = __hfma2(w0.h, h0[1], hc1);
      hc2 = __hfma2(w0.h, h0[2], hc2); hc3 = __hfma2(w0.h, h0[3], hc3);
      hc0 = __hfma2(w1.h, h1[0], hc0); hc1 = __hfma2(w1.h, h1[1], hc1);
      hc2 = __hfma2(w1.h, h1[2], hc2); hc3 = __hfma2(w1.h, h1[3], hc3);
      hc0 = __hfma2(w2.h, h2[0], hc0); hc1 = __hfma2(w2.h, h2[1], hc1);
      hc2 = __hfma2(w2.h, h2[2], hc2); hc3 = __hfma2(w2.h, h2[3], hc3);
      hc0 = __hfma2(w3.h, h3[0], hc0); hc1 = __hfma2(w3.h, h3[1], hc1);
      hc2 = __hfma2(w3.h, h3[2], hc2); hc3 = __hfma2(w3.h, h3[3], hc3);
      float2 f;
      f = __half22float2(hc0); a0.x += f.x; a0.y += f.y;
      f = __half22float2(hc1); a0.z += f.x; a0.w += f.y;
      f = __half22float2(hc2); a1.x += f.x; a1.y += f.y;
      f = __half22float2(hc3); a1.z += f.x; a1.w += f.y;
    };

    // 2-stage pipeline over j in [0, dr) step 16
    stage(0, va, pa);
    int j = 16;
    for (;;) {
      if (j >= dr) { compute(va, pa); break; }
      stage(j, vb, pb);
      compute(va, pa);
      j += 16;
      if (j >= dr) { compute(vb, pb); break; }
      stage(j, va, pa);
      compute(vb, pb);
      j += 16;
    }

    for (int jt = 64 + e; jt < d; jt += 4) {   // ultra-rare fallback: exact recompute
      const int s = col_src[begin + jt];
      const float2 a = AS[s];
      float e0 = a.x + adn.x; e0 = (e0 > 0.f) ? e0 : kNEG * e0;
      float e1 = a.y + adn.y; e1 = (e1 > 0.f) ? e1 : kNEG * e1;
      const float w = hsel ? __expf(e1) : __expf(e0);
      union { uint4 u; __half2 h[4]; } raw;
      raw.u = *(const uint4*)(H2 + (size_t)s * 128 + 8 * q);
      const float2 f0 = __half22float2(raw.h[0]);
      const float2 f1 = __half22float2(raw.h[1]);
      const float2 f2 = __half22float2(raw.h[2]);
      const float2 f3 = __half22float2(raw.h[3]);
      a0.x = fmaf(w, f0.x, a0.x); a0.y = fmaf(w, f0.y, a0.y);
      a0.z = fmaf(w, f1.x, a0.z); a0.w = fmaf(w, f1.y, a0.w);
      a1.x = fmaf(w, f2.x, a1.x); a1.y = fmaf(w, f2.y, a1.y);
      a1.z = fmaf(w, f3.x, a1.z); a1.w = fmaf(w, f3.y, a1.w);
    }
    // combine 4 edge-streams
#pragma unroll
    for (int off = 32; off >= 16; off >>= 1) {
      a0.x += __shfl_xor(a0.x, off); a0.y += __shfl_xor(a0.y, off);
      a0.z += __shfl_xor(a0.z, off); a0.w += __shfl_xor(a0.w, off);
      a1.x += __shfl_xor(a1.x, off); a1.y += __shfl_xor(a1.y, off);
      a1.z += __shfl_xor(a1.z, off); a1.w += __shfl_xor(a1.w, off);
    }
    if (lane < 16) {
      const int ch = 8 * q;
      const float4 b0v = *(const float4*)(bias + ch);
      const float4 b1v = *(const float4*)(bias + ch + 4);
      float4 o0, o1;
      o0.x = a0.x * inv + b0v.x; o0.y = a0.y * inv + b0v.y;
      o0.z = a0.z * inv + b0v.z; o0.w = a0.w * inv + b0v.w;
      o1.x = a1.x * inv + b1v.x; o1.y = a1.y * inv + b1v.y;
      o1.z = a1.z * inv + b1v.z; o1.w = a1.w * inv + b1v.w;
      o0.x = (o0.x > 0.f) ? o0.x : expm1f(o0.x);
      o0.y = (o0.y > 0.f) ? o0.y : expm1f(o0.y);
      o0.z = (o0.z > 0.f) ? o0.z : expm1f(o0.z);
      o0.w = (o0.w > 0.f) ? o0.w : expm1f(o0.w);
      o1.x = (o1.x > 0.f) ? o1.x : expm1f(o1.x);
      o1.y = (o1.y > 0.f) ? o1.y : expm1f(o1.y);
      o1.z = (o1.z > 0.f) ? o1.z : expm1f(o1.z);
      o1.w = (o1.w > 0.f) ? o1.w : expm1f(o1.w);
      union { __half2 h[4]; uint4 u; } pk;
      pk.h[0] = __floats2half2_rn(o0.x, o0.y);
      pk.h[1] = __floats2half2_rn(o0.z, o0.w);
      pk.h[2] = __floats2half2_rn(o1.x, o1.y);
      pk.h[3] = __floats2half2_rn(o1.z, o1.w);
      *(uint4*)((__half*)OUT + (size_t)node * 128 + ch) = pk.u;
    }
  } else {
    const int e = lane >> 3;        // edge-stream 0..7
    const int q = lane & 7;         // channels 4q..4q+3
    const int hsel = (q >= 4);
    const unsigned sel = hsel ? 0x03020302u : 0x01000100u;
    const float inv = hsel ? inv1 : inv0;
    __half2 hz; *(unsigned*)&hz = 0u;
    __half2 hc0 = hz, hc1 = hz;     // <=8 edges/lane in fp16 accum (dr<=64)

    uint2 va[2], vb[2];
    unsigned pa[2], pb[2];
    auto stage = [&](int j, uint2* v, unsigned* p) {
      const int j0 = j + e, j1 = j + 8 + e;
      const int s0 = __shfl(srcv, j0), s1 = __shfl(srcv, j1);
      p[0] = (unsigned)__shfl((int)pkw, j0);
      p[1] = (unsigned)__shfl((int)pkw, j1);
      v[0] = *(const uint2*)(H2 + (size_t)s0 * 32 + 4 * q);
      v[1] = *(const uint2*)(H2 + (size_t)s1 * 32 + 4 * q);
    };
    auto compute = [&](const uint2* v, const unsigned* p) {
      union { unsigned u; __half2 h; } w0, w1;
      w0.u = __builtin_amdgcn_perm(p[0], p[0], sel);
      w1.u = __builtin_amdgcn_perm(p[1], p[1], sel);
      const __half2* h0 = (const __half2*)&v[0];
      const __half2* h1 = (const __half2*)&v[1];
      hc0 = __hfma2(w0.h, h0[0], hc0); hc1 = __hfma2(w0.h, h0[1], hc1);
      hc0 = __hfma2(w1.h, h1[0], hc0); hc1 = __hfma2(w1.h, h1[1], hc1);
    };

    stage(0, va, pa);
    int j = 16;
    for (;;) {
      if (j >= dr) { compute(va, pa); break; }
      stage(j, vb, pb);
      compute(va, pa);
      j += 16;
      if (j >= dr) { compute(vb, pb); break; }
      stage(j, va, pa);
      compute(vb, pb);
      j += 16;
    }

    float4 acc;
    float2 f;
    f = __half22float2(hc0); acc.x = f.x; acc.y = f.y;
    f = __half22float2(hc1); acc.z = f.x; acc.w = f.y;
    for (int jt = 64 + e; jt < d; jt += 8) {   // ultra-rare fallback
      const int s = col_src[begin + jt];
      const float2 a = AS[s];
      float e0 = a.x + adn.x; e0 = (e0 > 0.f) ? e0 : kNEG * e0;
      float e1 = a.y + adn.y; e1 = (e1 > 0.f) ? e1 : kNEG * e1;
      const float w = hsel ? __expf(e1) : __expf(e0);
      union { uint2 u; __half2 h[2]; } raw;
      raw.u = *(const uint2*)(H2 + (size_t)s * 32 + 4 * q);
      const float2 f0 = __half22float2(raw.h[0]);
      const float2 f1 = __half22float2(raw.h[1]);
      acc.x = fmaf(w, f0.x, acc.x); acc.y = fmaf(w, f0.y, acc.y);
      acc.z = fmaf(w, f1.x, acc.z); acc.w = fmaf(w, f1.y, acc.w);
    }
    // combine 8 edge-streams
#pragma unroll
    for (int off = 32; off >= 8; off >>= 1) {
      acc.x += __shfl_xor(acc.x, off); acc.y += __shfl_xor(acc.y, off);
      acc.z += __shfl_xor(acc.z, off); acc.w += __shfl_xor(acc.w, off);
    }
    acc.x *= inv; acc.y *= inv; acc.z *= inv; acc.w *= inv;
    // head mean: q pairs with q+4 (channel c with c+16)
    const float px = __shfl_xor(acc.x, 4);
    const float py = __shfl_xor(acc.y, 4);
    const float pz = __shfl_xor(acc.z, 4);
    const float pw2 = __shfl_xor(acc.w, 4);
    if (lane < 4) {
      const int ch = 4 * q;
      const float4 bv = *(const float4*)(bias + ch);
      float4 o;
      o.x = 0.5f * (acc.x + px) + bv.x;
      o.y = 0.5f * (acc.y + py) + bv.y;
      o.z = 0.5f * (acc.z + pz) + bv.z;
      o.w = 0.5f * (acc.w + pw2) + bv.w;
      *(float4*)((float*)OUT + (size_t)node * 16 + ch) = o;
    }
  }
}

// ---------------- host launcher ----------------
extern "C" void kernel_launch(void* const* d_in, const int* in_sizes, int n_in,
                              void* d_out, int out_size, void* d_ws, size_t ws_size,
                              hipStream_t stream) {
  const float* x   = (const float*)d_in[0];
  const int*   ei  = (const int*)d_in[1];
  const float* W0  = (const float*)d_in[2];
  const float* as0 = (const float*)d_in[3];
  const float* ad0 = (const float*)d_in[4];
  const float* b0  = (const float*)d_in[5];
  const float* W1  = (const float*)d_in[6];
  const float* as1 = (const float*)d_in[7];
  const float* ad1 = (const float*)d_in[8];
  const float* b1  = (const float*)d_in[9];
  const float* W2  = (const float*)d_in[10];
  const float* as2 = (const float*)d_in[11];
  const float* ad2 = (const float*)d_in[12];
  const float* b2  = (const float*)d_in[13];
  float* out = (float*)d_out;

  size_t off = 0;
  auto alloc = [&](size_t bytes) -> void* {
    void* p = (char*)d_ws + off;
    off += (bytes + 255) & ~(size_t)255;
    return p;
  };
  int*    row_beg = (int*)alloc(sizeof(int) * kN);
  int*    row_cnt = (int*)alloc(sizeof(int) * kN);
  int*    bcnt    = (int*)alloc(sizeof(int) * NBUCK);
  int*    col_src = (int*)alloc(sizeof(int) * (size_t)NBUCK * CAPB);
  float2* AS      = (float2*)alloc(sizeof(float2) * kN);
  float2* AD      = (float2*)alloc(sizeof(float2) * kN);
  __half* H2      = (__half*)alloc(sizeof(__half) * (size_t)kN * 128);
  __half* actA    = (__half*)alloc(sizeof(__half) * (size_t)kN * 128);
  __half* actB    = (__half*)alloc(sizeof(__half) * (size_t)kN * 128);
  __half* Wt0     = (__half*)alloc(sizeof(__half) * 128 * 128);
  __half* Wt1     = (__half*)alloc(sizeof(__half) * 128 * 128);
  __half* Wt2     = (__half*)alloc(sizeof(__half) * 32 * 128);
  unsigned* part  = (unsigned*)actA;   // 8MB <= 12.8MB; dead before layer-0 agg writes actA
  (void)ws_size; (void)in_sizes; (void)n_in; (void)out_size;

  // ---- CSR build + W prep (edge list identical for all layers) ----
  prep_w_kernel<<<144, 256, 0, stream>>>(W0, W1, W2, Wt0, Wt1, Wt2, bcnt);
  partition_kernel<<<PGRID, 256, 0, stream>>>(ei, bcnt, part);
  finalize_kernel<<<NBUCK, 512, 0, stream>>>(part, bcnt, row_beg, row_cnt, col_src);

  const int tgrid = (kN + 63) / 64;   // 782
  const int ngrid = kN / 4;           // 12500

  // ---- layer 0 ----
  mfma_transform_kernel<128, float><<<tgrid, 256, 0, stream>>>(x, Wt0, as0, ad0, H2, AS, AD, kN);
  agg_kernel<64, 0, __half><<<ngrid, 256, 0, stream>>>(H2, AS, AD, row_beg, row_cnt, col_src, b0, actA);

  // ---- layer 1 ----
  mfma_transform_kernel<128, __half><<<tgrid, 256, 0, stream>>>(actA, Wt1, as1, ad1, H2, AS, AD, kN);
  agg_kernel<64, 0, __half><<<ngrid, 256, 0, stream>>>(H2, AS, AD, row_beg, row_cnt, col_src, b1, actB);

  // ---- layer 2 ----
  mfma_transform_kernel<32, __half><<<tgrid, 256, 0, stream>>>(actB, Wt2, as2, ad2, H2, AS, AD, kN);
  agg_kernel<16, 1, float><<<ngrid, 256, 0, stream>>>(H2, AS, AD, row_beg, row_cnt, col_src, b2, out);
}

// Round 14
// 251.495 us; speedup vs baseline: 1.3166x; 1.0234x over previous
//
#include <hip/hip_runtime.h>
#include <hip/hip_fp16.h>
#include <cstdint>
#include <cstddef>
#include <type_traits>

// ---------------- problem constants ----------------
constexpr int kN   = 50000;            // nodes
constexpr int kE   = 1600000;          // edges (before self loops)
constexpr int kET  = kE + kN;          // total edges incl self loops
constexpr float kNEG = 0.2f;
constexpr int NBUCK = (kN + 127) / 128;        // 391 buckets of 128 dst nodes
constexpr int CAPB  = 5120;                    // bucket capacity (mean 4220, +13 sigma)
constexpr int PCHUNK = 2048;                   // edges per partition block
constexpr int PGRID = (kET + PCHUNK - 1) / PCHUNK;

typedef _Float16 f16x8 __attribute__((ext_vector_type(8)));
typedef float    f32x4 __attribute__((ext_vector_type(4)));

// ---------------- CSR build: single-pass bucketed partition (+ fused W prep) ----------------
__global__ __launch_bounds__(256) void partition_kernel(
    const int* __restrict__ ei, int* __restrict__ bcnt, unsigned* __restrict__ part,
    const float* __restrict__ W0, const float* __restrict__ W1,
    const float* __restrict__ W2, __half* __restrict__ Wt0,
    __half* __restrict__ Wt1, __half* __restrict__ Wt2) {
  __shared__ int hist[NBUCK];
  __shared__ int resv[NBUCK];
  __shared__ int lcnt[NBUCK];
  const int t = threadIdx.x;
  // fused W transpose+fp16 (first 144 blocks, one pass)
  {
    const int gi = blockIdx.x * 256 + t;
    if (gi < 16384) {
      const int k = gi >> 7, c = gi & 127;
      Wt0[c * 128 + k] = __float2half_rn(W0[gi]);
    } else if (gi < 32768) {
      const int j = gi - 16384, k = j >> 7, c = j & 127;
      Wt1[c * 128 + k] = __float2half_rn(W1[j]);
    } else if (gi < 36864) {
      const int j = gi - 32768, k = j >> 5, c = j & 31;
      Wt2[c * 128 + k] = __float2half_rn(W2[j]);
    }
  }
  for (int i = t; i < NBUCK; i += 256) hist[i] = 0;
  __syncthreads();
  const int c0 = blockIdx.x * PCHUNK;
  const int cend = (c0 + PCHUNK < kET) ? c0 + PCHUNK : kET;
  for (int i = c0 + t; i < cend; i += 256) {
    const int dst = (i < kE) ? ei[kE + i] : (i - kE);
    atomicAdd(&hist[dst >> 7], 1);
  }
  __syncthreads();
  for (int i = t; i < NBUCK; i += 256) {
    lcnt[i] = 0;
    if (hist[i]) resv[i] = i * CAPB + atomicAdd(&bcnt[i], hist[i]);
  }
  __syncthreads();
  for (int i = c0 + t; i < cend; i += 256) {
    int src, dst;
    if (i < kE) { src = ei[i]; dst = ei[kE + i]; }
    else        { src = i - kE; dst = src; }
    const int b = dst >> 7;
    const int off = atomicAdd(&lcnt[b], 1);
    part[resv[b] + off] = ((unsigned)(dst & 127) << 16) | (unsigned)src;
  }
}

__global__ __launch_bounds__(256) void finalize_kernel(const unsigned* __restrict__ part,
                                                       const int* __restrict__ bcnt,
                                                       int* __restrict__ row_beg,
                                                       int* __restrict__ row_cnt,
                                                       int* __restrict__ col_src) {
  __shared__ int cnt[128];
  __shared__ int sc[128];
  __shared__ int nbase[128];
  const int b = blockIdx.x, t = threadIdx.x;
  const int lo = b * CAPB;
  const int hi = lo + bcnt[b];
  if (t < 128) cnt[t] = 0;
  __syncthreads();
  for (int j = lo + t; j < hi; j += 256) atomicAdd(&cnt[part[j] >> 16], 1);
  __syncthreads();
  if (t < 128) sc[t] = cnt[t];
  __syncthreads();
  for (int off = 1; off < 128; off <<= 1) {
    int v = 0;
    if (t < 128 && t >= off) v = sc[t - off];
    __syncthreads();
    if (t < 128) sc[t] += v;
    __syncthreads();
  }
  if (t < 128) {
    const int c = cnt[t];
    nbase[t] = lo + sc[t] - c;
    const int node = b * 128 + t;
    if (node < kN) { row_beg[node] = nbase[t]; row_cnt[node] = c; }
    cnt[t] = 0;
  }
  __syncthreads();
  for (int j = lo + t; j < hi; j += 256) {
    const unsigned v = part[j];
    const int nl = v >> 16;
    const int pos = nbase[nl] + atomicAdd(&cnt[nl], 1);
    col_src[pos] = (int)(v & 0xffffu);
  }
}

// ---------------- MFMA transform + fused alpha ----------------
// H2[r][c] (fp16 flat) = X[r][:] @ W[:, c], via mfma_f32_16x16x32_f16 with
// A = Wt rows (c is the M-dim -> lane holds 4 consecutive c), B = X rows.
template<int NCOL, typename TIN>
__global__ __launch_bounds__(256) void mfma_transform_kernel(
    const TIN* __restrict__ X, const __half* __restrict__ Wt,
    const float* __restrict__ asf, const float* __restrict__ adf,
    __half* __restrict__ H2, float2* __restrict__ AS, float2* __restrict__ AD, int n) {
  constexpr int NT = NCOL / 16;
  const int wid  = threadIdx.x >> 6;
  const int lane = threadIdx.x & 63;
  const int rbase = blockIdx.x * 64 + wid * 16;
  if (rbase >= n) return;
  const int r  = rbase + (lane & 15);
  const int kg = (lane >> 4) * 8;
  const _Float16* __restrict__ Wf = (const _Float16*)Wt;

  f32x4 acc[NT];
#pragma unroll
  for (int t = 0; t < NT; t++) acc[t] = (f32x4){0.f, 0.f, 0.f, 0.f};

#pragma unroll
  for (int kc = 0; kc < 4; kc++) {
    const int kh = kc * 32 + kg;
    f16x8 bfrag;
    if constexpr (std::is_same<TIN, float>::value) {
      const float4 v0 = *(const float4*)(X + (size_t)r * 128 + kh);
      const float4 v1 = *(const float4*)(X + (size_t)r * 128 + kh + 4);
      bfrag[0] = (_Float16)v0.x; bfrag[1] = (_Float16)v0.y;
      bfrag[2] = (_Float16)v0.z; bfrag[3] = (_Float16)v0.w;
      bfrag[4] = (_Float16)v1.x; bfrag[5] = (_Float16)v1.y;
      bfrag[6] = (_Float16)v1.z; bfrag[7] = (_Float16)v1.w;
    } else {
      bfrag = *(const f16x8*)((const _Float16*)X + (size_t)r * 128 + kh);
    }
#pragma unroll
    for (int t = 0; t < NT; t++) {
      const f16x8 afrag = *(const f16x8*)(Wf + (size_t)(t * 16 + (lane & 15)) * 128 + kh);
      acc[t] = __builtin_amdgcn_mfma_f32_16x16x32_f16(afrag, bfrag, acc[t], 0, 0, 0);
    }
  }

  // epilogue: H2 store (4 consecutive channels / lane / tile) + alpha partials
  const int c4 = (lane >> 4) * 4;
  float s0 = 0.f, s1 = 0.f, d0 = 0.f, d1 = 0.f;
#pragma unroll
  for (int t = 0; t < NT; t++) {
    const int c0 = t * 16 + c4;
    const float4 av = *(const float4*)(asf + c0);
    const float4 dv = *(const float4*)(adf + c0);
    const float ps = acc[t][0] * av.x + acc[t][1] * av.y + acc[t][2] * av.z + acc[t][3] * av.w;
    const float pd = acc[t][0] * dv.x + acc[t][1] * dv.y + acc[t][2] * dv.z + acc[t][3] * dv.w;
    if (t < NT / 2) { s0 += ps; d0 += pd; } else { s1 += ps; d1 += pd; }
    union { __half2 h[2]; uint2 u; } pk;
    pk.h[0] = __floats2half2_rn(acc[t][0], acc[t][1]);
    pk.h[1] = __floats2half2_rn(acc[t][2], acc[t][3]);
    *(uint2*)(H2 + (size_t)r * NCOL + c0) = pk.u;
  }
#pragma unroll
  for (int off = 16; off <= 32; off <<= 1) {
    s0 += __shfl_xor(s0, off); s1 += __shfl_xor(s1, off);
    d0 += __shfl_xor(d0, off); d1 += __shfl_xor(d1, off);
  }
  if (lane < 16) {
    AS[rbase + lane] = make_float2(s0, s1);
    AD[rbase + lane] = make_float2(d0, d1);
  }
}

// ---------------- fused softmax + aggregate (barrier-free, wave-per-node) ----------------
// R11-proven form: weights in REGISTERS (one edge per lane, d<=64 fast path);
// pass B batches 4 independent gathers per iteration (compiler-scheduled, 28 VGPR).
// MODE 0 (C=64): OUT[n,128]=elu(agg+bias) fp16; 4 streams x 16 lanes x 16B, 4-deep.
// MODE 1 (C=16): OUT[n,16]=mean_heads(agg)+b fp32; 8 streams x 8 lanes x 8B, 2-deep.
template<int C, int MODE, typename TOUT>
__global__ __launch_bounds__(256) void agg_kernel(
    const __half* __restrict__ H2, const float2* __restrict__ AS,
    const float2* __restrict__ AD, const int* __restrict__ row_beg,
    const int* __restrict__ row_cnt, const int* __restrict__ col_src,
    const float* __restrict__ bias, TOUT* __restrict__ OUT) {
  const int wid  = threadIdx.x >> 6;
  const int lane = threadIdx.x & 63;
  const int node = blockIdx.x * 4 + wid;

  const int begin = row_beg[node];
  const int d = row_cnt[node];
  const float2 adn = AD[node];

  // ---- pass A: one edge per lane, weights in registers ----
  int srcv = 0;
  unsigned pkw = 0;                 // half2: low = w_head0, high = w_head1
  float sum0 = 0.f, sum1 = 0.f;
  if (lane < d) {
    srcv = col_src[begin + lane];
    const float2 a = AS[srcv];
    float e0 = a.x + adn.x; e0 = (e0 > 0.f) ? e0 : kNEG * e0;
    float e1 = a.y + adn.y; e1 = (e1 > 0.f) ? e1 : kNEG * e1;
    sum0 = __expf(e0); sum1 = __expf(e1);
    const __half2 ph = __floats2half2_rn(sum0, sum1);
    pkw = *(const unsigned*)&ph;
  }
  for (int j = 64 + lane; j < d; j += 64) {    // ultra-rare d>64 tail (sums only)
    const int s = col_src[begin + j];
    const float2 a = AS[s];
    float e0 = a.x + adn.x; e0 = (e0 > 0.f) ? e0 : kNEG * e0;
    float e1 = a.y + adn.y; e1 = (e1 > 0.f) ? e1 : kNEG * e1;
    sum0 += __expf(e0); sum1 += __expf(e1);
  }
#pragma unroll
  for (int off = 32; off >= 1; off >>= 1) {
    sum0 += __shfl_xor(sum0, off);
    sum1 += __shfl_xor(sum1, off);
  }
  const float inv0 = 1.0f / (sum0 + 1e-16f);
  const float inv1 = 1.0f / (sum1 + 1e-16f);

  const int dr = (d < 64) ? d : 64;            // register-held edges

  if constexpr (MODE == 0) {
    const int e = lane >> 4;        // edge-stream 0..3
    const int q = lane & 15;        // channels 8q..8q+7
    const int hsel = (q >= 8);
    const unsigned sel = hsel ? 0x03020302u : 0x01000100u;
    const float inv = hsel ? inv1 : inv0;
    float4 a0 = make_float4(0.f, 0.f, 0.f, 0.f);
    float4 a1 = make_float4(0.f, 0.f, 0.f, 0.f);
    for (int j = 0; j < dr; j += 16) {
      // 4 independent edges per lane-group: j+e, j+4+e, j+8+e, j+12+e (all <= 63)
      const int j0 = j + e, j1 = j + 4 + e, j2 = j + 8 + e, j3 = j + 12 + e;
      const int s0 = __shfl(srcv, j0), s1 = __shfl(srcv, j1),
                s2 = __shfl(srcv, j2), s3 = __shfl(srcv, j3);
      const unsigned p0 = __shfl((int)pkw, j0), p1 = __shfl((int)pkw, j1),
                     p2 = __shfl((int)pkw, j2), p3 = __shfl((int)pkw, j3);
      union { uint4 u; __half2 h[4]; } r0, r1, r2, r3;
      r0.u = *(const uint4*)(H2 + (size_t)s0 * 128 + 8 * q);
      r1.u = *(const uint4*)(H2 + (size_t)s1 * 128 + 8 * q);
      r2.u = *(const uint4*)(H2 + (size_t)s2 * 128 + 8 * q);
      r3.u = *(const uint4*)(H2 + (size_t)s3 * 128 + 8 * q);
      union { unsigned u; __half2 h; } w0, w1, w2, w3;
      w0.u = __builtin_amdgcn_perm(p0, p0, sel);
      w1.u = __builtin_amdgcn_perm(p1, p1, sel);
      w2.u = __builtin_amdgcn_perm(p2, p2, sel);
      w3.u = __builtin_amdgcn_perm(p3, p3, sel);
      __half2 hz; *(unsigned*)&hz = 0u;
      __half2 hc0 = hz, hc1 = hz, hc2 = hz, hc3 = hz;
      hc0 = __hfma2(w0.h, r0.h[0], hc0); hc1 = __hfma2(w0.h, r0.h[1], hc1);
      hc2 = __hfma2(w0.h, r0.h[2], hc2); hc3 = __hfma2(w0.h, r0.h[3], hc3);
      hc0 = __hfma2(w1.h, r1.h[0], hc0); hc1 = __hfma2(w1.h, r1.h[1], hc1);
      hc2 = __hfma2(w1.h, r1.h[2], hc2); hc3 = __hfma2(w1.h, r1.h[3], hc3);
      hc0 = __hfma2(w2.h, r2.h[0], hc0); hc1 = __hfma2(w2.h, r2.h[1], hc1);
      hc2 = __hfma2(w2.h, r2.h[2], hc2); hc3 = __hfma2(w2.h, r2.h[3], hc3);
      hc0 = __hfma2(w3.h, r3.h[0], hc0); hc1 = __hfma2(w3.h, r3.h[1], hc1);
      hc2 = __hfma2(w3.h, r3.h[2], hc2); hc3 = __hfma2(w3.h, r3.h[3], hc3);
      float2 f;
      f = __half22float2(hc0); a0.x += f.x; a0.y += f.y;
      f = __half22float2(hc1); a0.z += f.x; a0.w += f.y;
      f = __half22float2(hc2); a1.x += f.x; a1.y += f.y;
      f = __half22float2(hc3); a1.z += f.x; a1.w += f.y;
    }
    for (int jt = 64 + e; jt < d; jt += 4) {   // ultra-rare fallback: exact recompute
      const int s = col_src[begin + jt];
      const float2 a = AS[s];
      float e0 = a.x + adn.x; e0 = (e0 > 0.f) ? e0 : kNEG * e0;
      float e1 = a.y + adn.y; e1 = (e1 > 0.f) ? e1 : kNEG * e1;
      const float w = hsel ? __expf(e1) : __expf(e0);
      union { uint4 u; __half2 h[4]; } raw;
      raw.u = *(const uint4*)(H2 + (size_t)s * 128 + 8 * q);
      const float2 f0 = __half22float2(raw.h[0]);
      const float2 f1 = __half22float2(raw.h[1]);
      const float2 f2 = __half22float2(raw.h[2]);
      const float2 f3 = __half22float2(raw.h[3]);
      a0.x = fmaf(w, f0.x, a0.x); a0.y = fmaf(w, f0.y, a0.y);
      a0.z = fmaf(w, f1.x, a0.z); a0.w = fmaf(w, f1.y, a0.w);
      a1.x = fmaf(w, f2.x, a1.x); a1.y = fmaf(w, f2.y, a1.y);
      a1.z = fmaf(w, f3.x, a1.z); a1.w = fmaf(w, f3.y, a1.w);
    }
    // combine 4 edge-streams
#pragma unroll
    for (int off = 32; off >= 16; off >>= 1) {
      a0.x += __shfl_xor(a0.x, off); a0.y += __shfl_xor(a0.y, off);
      a0.z += __shfl_xor(a0.z, off); a0.w += __shfl_xor(a0.w, off);
      a1.x += __shfl_xor(a1.x, off); a1.y += __shfl_xor(a1.y, off);
      a1.z += __shfl_xor(a1.z, off); a1.w += __shfl_xor(a1.w, off);
    }
    if (lane < 16) {
      const int ch = 8 * q;
      const float4 b0v = *(const float4*)(bias + ch);
      const float4 b1v = *(const float4*)(bias + ch + 4);
      float4 o0, o1;
      o0.x = a0.x * inv + b0v.x; o0.y = a0.y * inv + b0v.y;
      o0.z = a0.z * inv + b0v.z; o0.w = a0.w * inv + b0v.w;
      o1.x = a1.x * inv + b1v.x; o1.y = a1.y * inv + b1v.y;
      o1.z = a1.z * inv + b1v.z; o1.w = a1.w * inv + b1v.w;
      o0.x = (o0.x > 0.f) ? o0.x : expm1f(o0.x);
      o0.y = (o0.y > 0.f) ? o0.y : expm1f(o0.y);
      o0.z = (o0.z > 0.f) ? o0.z : expm1f(o0.z);
      o0.w = (o0.w > 0.f) ? o0.w : expm1f(o0.w);
      o1.x = (o1.x > 0.f) ? o1.x : expm1f(o1.x);
      o1.y = (o1.y > 0.f) ? o1.y : expm1f(o1.y);
      o1.z = (o1.z > 0.f) ? o1.z : expm1f(o1.z);
      o1.w = (o1.w > 0.f) ? o1.w : expm1f(o1.w);
      union { __half2 h[4]; uint4 u; } pk;
      pk.h[0] = __floats2half2_rn(o0.x, o0.y);
      pk.h[1] = __floats2half2_rn(o0.z, o0.w);
      pk.h[2] = __floats2half2_rn(o1.x, o1.y);
      pk.h[3] = __floats2half2_rn(o1.z, o1.w);
      *(uint4*)((__half*)OUT + (size_t)node * 128 + ch) = pk.u;
    }
  } else {
    const int e = lane >> 3;        // edge-stream 0..7
    const int q = lane & 7;         // channels 4q..4q+3
    const int hsel = (q >= 4);
    const unsigned sel = hsel ? 0x03020302u : 0x01000100u;
    const float inv = hsel ? inv1 : inv0;
    __half2 hz; *(unsigned*)&hz = 0u;
    __half2 hc0 = hz, hc1 = hz;     // <=8 edges/lane in fp16 accum (dr<=64)
    for (int j = 0; j < dr; j += 16) {
      const int j0 = j + e, j1 = j + 8 + e;              // <= 63 always
      const int s0 = __shfl(srcv, j0), s1 = __shfl(srcv, j1);
      const unsigned p0 = __shfl((int)pkw, j0), p1 = __shfl((int)pkw, j1);
      union { unsigned u; __half2 h; } w0, w1;
      w0.u = __builtin_amdgcn_perm(p0, p0, sel);
      w1.u = __builtin_amdgcn_perm(p1, p1, sel);
      union { uint2 u; __half2 h[2]; } r0, r1;
      r0.u = *(const uint2*)(H2 + (size_t)s0 * 32 + 4 * q);
      r1.u = *(const uint2*)(H2 + (size_t)s1 * 32 + 4 * q);
      hc0 = __hfma2(w0.h, r0.h[0], hc0); hc1 = __hfma2(w0.h, r0.h[1], hc1);
      hc0 = __hfma2(w1.h, r1.h[0], hc0); hc1 = __hfma2(w1.h, r1.h[1], hc1);
    }
    float4 acc;
    float2 f;
    f = __half22float2(hc0); acc.x = f.x; acc.y = f.y;
    f = __half22float2(hc1); acc.z = f.x; acc.w = f.y;
    for (int jt = 64 + e; jt < d; jt += 8) {   // ultra-rare fallback
      const int s = col_src[begin + jt];
      const float2 a = AS[s];
      float e0 = a.x + adn.x; e0 = (e0 > 0.f) ? e0 : kNEG * e0;
      float e1 = a.y + adn.y; e1 = (e1 > 0.f) ? e1 : kNEG * e1;
      const float w = hsel ? __expf(e1) : __expf(e0);
      union { uint2 u; __half2 h[2]; } raw;
      raw.u = *(const uint2*)(H2 + (size_t)s * 32 + 4 * q);
      const float2 f0 = __half22float2(raw.h[0]);
      const float2 f1 = __half22float2(raw.h[1]);
      acc.x = fmaf(w, f0.x, acc.x); acc.y = fmaf(w, f0.y, acc.y);
      acc.z = fmaf(w, f1.x, acc.z); acc.w = fmaf(w, f1.y, acc.w);
    }
    // combine 8 edge-streams
#pragma unroll
    for (int off = 32; off >= 8; off >>= 1) {
      acc.x += __shfl_xor(acc.x, off); acc.y += __shfl_xor(acc.y, off);
      acc.z += __shfl_xor(acc.z, off); acc.w += __shfl_xor(acc.w, off);
    }
    acc.x *= inv; acc.y *= inv; acc.z *= inv; acc.w *= inv;
    // head mean: q pairs with q+4 (channel c with c+16)
    const float px = __shfl_xor(acc.x, 4);
    const float py = __shfl_xor(acc.y, 4);
    const float pz = __shfl_xor(acc.z, 4);
    const float pw2 = __shfl_xor(acc.w, 4);
    if (lane < 4) {
      const int ch = 4 * q;
      const float4 bv = *(const float4*)(bias + ch);
      float4 o;
      o.x = 0.5f * (acc.x + px) + bv.x;
      o.y = 0.5f * (acc.y + py) + bv.y;
      o.z = 0.5f * (acc.z + pz) + bv.z;
      o.w = 0.5f * (acc.w + pw2) + bv.w;
      *(float4*)((float*)OUT + (size_t)node * 16 + ch) = o;
    }
  }
}

// ---------------- host launcher ----------------
extern "C" void kernel_launch(void* const* d_in, const int* in_sizes, int n_in,
                              void* d_out, int out_size, void* d_ws, size_t ws_size,
                              hipStream_t stream) {
  const float* x   = (const float*)d_in[0];
  const int*   ei  = (const int*)d_in[1];
  const float* W0  = (const float*)d_in[2];
  const float* as0 = (const float*)d_in[3];
  const float* ad0 = (const float*)d_in[4];
  const float* b0  = (const float*)d_in[5];
  const float* W1  = (const float*)d_in[6];
  const float* as1 = (const float*)d_in[7];
  const float* ad1 = (const float*)d_in[8];
  const float* b1  = (const float*)d_in[9];
  const float* W2  = (const float*)d_in[10];
  const float* as2 = (const float*)d_in[11];
  const float* ad2 = (const float*)d_in[12];
  const float* b2  = (const float*)d_in[13];
  float* out = (float*)d_out;

  size_t off = 0;
  auto alloc = [&](size_t bytes) -> void* {
    void* p = (char*)d_ws + off;
    off += (bytes + 255) & ~(size_t)255;
    return p;
  };
  int*    row_beg = (int*)alloc(sizeof(int) * kN);
  int*    row_cnt = (int*)alloc(sizeof(int) * kN);
  int*    bcnt    = (int*)alloc(sizeof(int) * NBUCK);
  int*    col_src = (int*)alloc(sizeof(int) * (size_t)NBUCK * CAPB);
  float2* AS      = (float2*)alloc(sizeof(float2) * kN);
  float2* AD      = (float2*)alloc(sizeof(float2) * kN);
  __half* H2      = (__half*)alloc(sizeof(__half) * (size_t)kN * 128);
  __half* actA    = (__half*)alloc(sizeof(__half) * (size_t)kN * 128);
  __half* actB    = (__half*)alloc(sizeof(__half) * (size_t)kN * 128);
  __half* Wt0     = (__half*)alloc(sizeof(__half) * 128 * 128);
  __half* Wt1     = (__half*)alloc(sizeof(__half) * 128 * 128);
  __half* Wt2     = (__half*)alloc(sizeof(__half) * 32 * 128);
  unsigned* part  = (unsigned*)actA;   // 8MB <= 12.8MB; dead before layer-0 agg writes actA
  (void)ws_size; (void)in_sizes; (void)n_in; (void)out_size;

  // ---- CSR build + fused W prep (edge list identical for all layers) ----
  hipMemsetAsync(bcnt, 0, sizeof(int) * NBUCK, stream);
  partition_kernel<<<PGRID, 256, 0, stream>>>(ei, bcnt, part, W0, W1, W2, Wt0, Wt1, Wt2);
  finalize_kernel<<<NBUCK, 256, 0, stream>>>(part, bcnt, row_beg, row_cnt, col_src);

  const int tgrid = (kN + 63) / 64;   // 782
  const int ngrid = kN / 4;           // 12500

  // ---- layer 0 ----
  mfma_transform_kernel<128, float><<<tgrid, 256, 0, stream>>>(x, Wt0, as0, ad0, H2, AS, AD, kN);
  agg_kernel<64, 0, __half><<<ngrid, 256, 0, stream>>>(H2, AS, AD, row_beg, row_cnt, col_src, b0, actA);

  // ---- layer 1 ----
  mfma_transform_kernel<128, __half><<<tgrid, 256, 0, stream>>>(actA, Wt1, as1, ad1, H2, AS, AD, kN);
  agg_kernel<64, 0, __half><<<ngrid, 256, 0, stream>>>(H2, AS, AD, row_beg, row_cnt, col_src, b1, actB);

  // ---- layer 2 ----
  mfma_transform_kernel<32, __half><<<tgrid, 256, 0, stream>>>(actB, Wt2, as2, ad2, H2, AS, AD, kN);
  agg_kernel<16, 1, float><<<ngrid, 256, 0, stream>>>(H2, AS, AD, row_beg, row_cnt, col_src, b2, out);
}